// Round 7
// baseline (129.107 us; speedup 1.0000x reference)
//
#include <hip/hip_runtime.h>
#include <hip/hip_bf16.h>
#include <hip/hip_fp16.h>
#include <math.h>

#define BB 8
#define HH 96
#define WW 96
#define HW 9216
#define BN_EPS 1e-5f

typedef _Float16 f16x2 __attribute__((ext_vector_type(2)));
typedef _Float16 f16x8 __attribute__((ext_vector_type(8)));
typedef float f32x4 __attribute__((ext_vector_type(4)));

union F8 { f16x8 v8; f16x2 h2[4]; uint4 u4; };
union HU { _Float16 h; unsigned short u; };
union UH2 { unsigned u; f16x2 h; };

// ---- workspace layout (bytes) ----
#define OFF_W4   0
#define SZ_W4    (BB*9*HW*16)          // uint4 per (b,k,pixel): 4 replicated-f16 bilinear wts
#define OFF_XT   (OFF_W4 + SZ_W4)
#define SZ_XT    (BB*HW*64*2)          // fp16 x transposed (B,H,W,C)
#define OFF_XY   (OFF_XT + SZ_XT)
#define SZ_XY    (BB*9*HW*4)           // packed clamped tap indices
#define OFF_WB   (OFF_XY + SZ_XY)
#define SZ_WB    (64*576*2)            // wB[o][k*64+c] fp16 (main conv)
#define OFF_WO   (OFF_WB + SZ_WB)
#define SZ_WO    (32*576*2)            // wOff[oc][kk*64+c] fp16
#define OFF_BN   (OFF_WO + SZ_WO)
#define SZ_BN    (64*2*4)              // bnS[64], bnB[64]

// ---------------- prep: weight transposes + BN fold ----------------
__global__ __launch_bounds__(256) void prep_kernel(
    const float* __restrict__ weight, const float* __restrict__ offw,
    const float* __restrict__ modw,
    const float* __restrict__ bias, const float* __restrict__ gamma,
    const float* __restrict__ beta, const float* __restrict__ mean,
    const float* __restrict__ var,
    _Float16* __restrict__ wB, _Float16* __restrict__ wOff,
    float* __restrict__ bnS, float* __restrict__ bnB) {
  int tid = blockIdx.x * 256 + threadIdx.x;
  if (tid < 64 * 576) {
    int o = tid / 576, ck = tid % 576;
    int k = ck >> 6, c = ck & 63;                // ck = k*64 + c
    wB[tid] = (_Float16)weight[o * 576 + c * 9 + k];
  }
  int t2 = tid - 64 * 576;
  if (t2 >= 0 && t2 < 32 * 576) {
    int oc = t2 / 576, kcol = t2 % 576;
    int kk = kcol >> 6, c = kcol & 63;           // kcol = kk*64 + c
    float v = 0.f;
    if (oc < 18)      v = offw[(oc * 64 + c) * 9 + kk];
    else if (oc < 27) v = modw[((oc - 18) * 64 + c) * 9 + kk];
    wOff[t2] = (_Float16)v;
  }
  int t3 = tid - (64 * 576 + 32 * 576);
  if (t3 >= 0 && t3 < 64) {
    float inv = gamma[t3] * rsqrtf(var[t3] + BN_EPS);
    bnS[t3] = inv;
    bnB[t3] = (bias[t3] - mean[t3]) * inv + beta[t3];
  }
}

// ---------------- LDS-tiled transpose x -> (B,H,W,C) fp16 ----------------
__global__ __launch_bounds__(256) void transpose_x_kernel(
    const float* __restrict__ x, _Float16* __restrict__ xT) {
  __shared__ float tile[64][65];
  int tid = threadIdx.x;
  int b = blockIdx.x / 144, hwb = (blockIdx.x % 144) * 64;
  int col = tid & 63, g = tid >> 6;
  float r[16];
#pragma unroll
  for (int it = 0; it < 16; ++it)
    r[it] = x[(b * 64 + it * 4 + g) * HW + hwb + col]; // coalesced 256B
  __builtin_amdgcn_sched_barrier(0);
#pragma unroll
  for (int it = 0; it < 16; ++it)
    tile[it * 4 + g][col] = r[it];
  __syncthreads();
#pragma unroll
  for (int it = 0; it < 16; ++it) {
    int p = it * 4 + g;
    xT[(size_t)(b * HW + hwb + p) * 64 + col] = (_Float16)tile[col][p];
  }
}

__device__ inline unsigned rep16(float w) {
  HU cv; cv.h = (_Float16)w;
  return 0x10001u * (unsigned)cv.u;
}

// ---------------- offset/mod conv via MFMA + fold into sample weights ----------------
__global__ __launch_bounds__(256, 8) void conv_offsets_kernel(
    const _Float16* __restrict__ xTh, const _Float16* __restrict__ wOff,
    const float* __restrict__ offb, const float* __restrict__ modb,
    uint4* __restrict__ w4, unsigned* __restrict__ xy) {
  __shared__ __attribute__((aligned(16))) _Float16 sN[3 * 34 * 70]; // stride-70 pad
  __shared__ float o_off[32 * 33];

  int tid = threadIdx.x;
  int lane = tid & 63;
  int wv = __builtin_amdgcn_readfirstlane(tid >> 6);

  int bi = blockIdx.x;                                  // 8 * 96 * 3
  int b = bi / 288, rem = bi % 288;
  int h = rem / 3, w0 = (rem % 3) * 32;

  // ---- stage 3 rows x 34 cols x 64 ch: batch-load to regs, then ds_write ----
  const _Float16* xb = xTh + (size_t)b * HW * 64;
  _Float16 sv[26];
#pragma unroll
  for (int i = 0; i < 26; ++i) {
    int p = wv + 4 * i;
    _Float16 v = (_Float16)0.f;
    if (p < 102) {
      int row = p / 34, col = p - row * 34;
      int y = h + row - 1, xx = w0 + col - 1;
      if ((y >= 0) && (y < HH) && (xx >= 0) && (xx < WW))
        v = xb[(size_t)(y * WW + xx) * 64 + lane];
    }
    sv[i] = v;
  }
  __builtin_amdgcn_sched_barrier(0);
#pragma unroll
  for (int i = 0; i < 26; ++i) {
    int p = wv + 4 * i;
    if (p < 102) {
      int row = p / 34, col = p - row * 34;
      sN[(row * 34 + col) * 70 + lane] = sv[i];
    }
  }
  __syncthreads();

  // ---- MFMA: C[32 px][32 oc], wave = (m-tile, n-tile) quadrant ----
  int r = lane & 15, g = lane >> 4;
  int mt = wv >> 1, nt = wv & 1;
  int px = mt * 16 + r;
  const _Float16* bp = wOff + (nt * 16 + r) * 576 + g * 8;
  f32x4 acc = {0.f, 0.f, 0.f, 0.f};
#pragma unroll
  for (int s = 0; s < 18; ++s) {
    int kk = s >> 1, ky = kk / 3, kx = kk - ky * 3;
    f16x8 a = *(const f16x8*)&sN[(ky * 34 + px + kx) * 70 + (s & 1) * 32 + g * 8];
    f16x8 bb = *(const f16x8*)(bp + s * 32);
    acc = __builtin_amdgcn_mfma_f32_16x16x32_f16(a, bb, acc, 0, 0, 0);
  }
#pragma unroll
  for (int j = 0; j < 4; ++j)
    o_off[(mt * 16 + g * 4 + j) * 33 + nt * 16 + r] = acc[j];
  __syncthreads();

  // ---- fold: sigmoid + bilinear weights (replicated f16 pairs) + taps ----
  for (int it = tid; it < 288; it += 256) {
    int pxx = it & 31, k = it >> 5;
    int ky = k / 3, kx = k - ky * 3;
    int w = w0 + pxx;

    float offy = o_off[pxx * 33 + 2 * k]     + offb[2 * k];
    float offx = o_off[pxx * 33 + 2 * k + 1] + offb[2 * k + 1];
    float mod  = 2.f / (1.f + __expf(-(o_off[pxx * 33 + 18 + k] + modb[k])));

    float py  = (float)(h - 1 + ky) + offy;
    float px_ = (float)(w - 1 + kx) + offx;
    float y0f = floorf(py), x0f = floorf(px_);
    float dy = py - y0f, dx = px_ - x0f;
    int y0 = (int)y0f, x0 = (int)x0f;
    int y1 = y0 + 1, x1 = x0 + 1;
    bool vy0 = (y0 >= 0) && (y0 < HH), vy1 = (y1 >= 0) && (y1 < HH);
    bool vx0 = (x0 >= 0) && (x0 < WW), vx1 = (x1 >= 0) && (x1 < WW);
    float w00 = (vy0 && vx0) ? (1.f - dy) * (1.f - dx) * mod : 0.f;
    float w01 = (vy0 && vx1) ? (1.f - dy) * dx * mod : 0.f;
    float w10 = (vy1 && vx0) ? dy * (1.f - dx) * mod : 0.f;
    float w11 = (vy1 && vx1) ? dy * dx * mod : 0.f;
    int y0c = min(max(y0, 0), HH - 1), y1c = min(max(y1, 0), HH - 1);
    int x0c = min(max(x0, 0), WW - 1), x1c = min(max(x1, 0), WW - 1);
    unsigned pk = (unsigned)y0c | ((unsigned)y1c << 8) |
                  ((unsigned)x0c << 16) | ((unsigned)x1c << 24);
    int idx = (b * 9 + k) * HW + h * WW + w;
    w4[idx] = make_uint4(rep16(w00), rep16(w01), rep16(w10), rep16(w11));
    xy[idx] = pk;
  }
}

__device__ inline F8 comb4(uint4 a, uint4 b, uint4 c, uint4 d,
                           f16x2 w00, f16x2 w01, f16x2 w10, f16x2 w11) {
  F8 A, B, C, D, R;
  A.u4 = a; B.u4 = b; C.u4 = c; D.u4 = d;
#pragma unroll
  for (int q = 0; q < 4; ++q)
    R.h2[q] = A.h2[q] * w00 + B.h2[q] * w01 + C.h2[q] * w10 + D.h2[q] * w11;
  return R;
}

// ---------------- fused deformable sample + MFMA GEMM + BN + ReLU ----------------
// Wave-independent: each wave owns 16 px x 64 oc, builds A-fragments in
// registers (no s_A LDS, no barriers), packed-fp16 bilinear combine.
__global__ __launch_bounds__(256, 3) void dcn_main_kernel(
    const _Float16* __restrict__ xT,
    const uint4* __restrict__ w4pk, const unsigned* __restrict__ xy,
    const _Float16* __restrict__ wB,
    const float* __restrict__ bnS, const float* __restrict__ bnB,
    float* __restrict__ out) {
  __shared__ float o_lds[4][64 * 17];

  int tid = threadIdx.x;
  int lane = tid & 63;
  int wv = __builtin_amdgcn_readfirstlane(tid >> 6);
  int r = lane & 15, g = lane >> 4;

  int bi = blockIdx.x;                                 // 8 * 144 blocks
  int b = bi / 144;
  int hwb0 = (bi - b * 144) * 64;
  int hwbw = hwb0 + wv * 16;                           // this wave's 16 px

  const _Float16* xb = xT + (size_t)b * HW * 64;
  const _Float16* xg = xb + g * 8;                     // channel sub-slice
  const _Float16* wBl = wB + r * 576 + g * 8;          // oc row base

  int idx0 = b * 9 * HW + hwbw + r;                    // per-lane (px=r) index

  // all 9 packed tap-coords up front (address deps for the gathers)
  unsigned pk[9];
#pragma unroll
  for (int k = 0; k < 9; ++k) pk[k] = xy[idx0 + k * HW];

  f32x4 acc[4] = {{0.f,0.f,0.f,0.f},{0.f,0.f,0.f,0.f},
                  {0.f,0.f,0.f,0.f},{0.f,0.f,0.f,0.f}};

#pragma unroll
  for (int k = 0; k < 9; ++k) {
    uint4 wq = w4pk[idx0 + k * HW];                    // replicated-f16 weights
    unsigned q = pk[k];
    int y0 = q & 255, y1 = (q >> 8) & 255, x0 = (q >> 16) & 255, x1 = q >> 24;
    int o00 = (y0 * WW + x0) << 6;
    int o01 = (y0 * WW + x1) << 6;
    int o10 = (y1 * WW + x0) << 6;
    int o11 = (y1 * WW + x1) << 6;

    // 8 independent tap gathers (16B/lane, dwordx4)
    uint4 t00a = *(const uint4*)(xg + o00);
    uint4 t01a = *(const uint4*)(xg + o01);
    uint4 t10a = *(const uint4*)(xg + o10);
    uint4 t11a = *(const uint4*)(xg + o11);
    uint4 t00b = *(const uint4*)(xg + o00 + 32);
    uint4 t01b = *(const uint4*)(xg + o01 + 32);
    uint4 t10b = *(const uint4*)(xg + o10 + 32);
    uint4 t11b = *(const uint4*)(xg + o11 + 32);

    // 8 B-fragment loads (L1-hot, same for every wave)
    uint4 bv0 = *(const uint4*)(wBl + 0 * 9216 + k * 64);
    uint4 bv1 = *(const uint4*)(wBl + 1 * 9216 + k * 64);
    uint4 bv2 = *(const uint4*)(wBl + 2 * 9216 + k * 64);
    uint4 bv3 = *(const uint4*)(wBl + 3 * 9216 + k * 64);
    uint4 bv4 = *(const uint4*)(wBl + 0 * 9216 + k * 64 + 32);
    uint4 bv5 = *(const uint4*)(wBl + 1 * 9216 + k * 64 + 32);
    uint4 bv6 = *(const uint4*)(wBl + 2 * 9216 + k * 64 + 32);
    uint4 bv7 = *(const uint4*)(wBl + 3 * 9216 + k * 64 + 32);

    UH2 c0, c1, c2, c3;
    c0.u = wq.x; c1.u = wq.y; c2.u = wq.z; c3.u = wq.w;

    F8 fh0 = comb4(t00a, t01a, t10a, t11a, c0.h, c1.h, c2.h, c3.h);
    F8 fh1 = comb4(t00b, t01b, t10b, t11b, c0.h, c1.h, c2.h, c3.h);

    F8 bb;
    bb.u4 = bv0; acc[0] = __builtin_amdgcn_mfma_f32_16x16x32_f16(fh0.v8, bb.v8, acc[0], 0, 0, 0);
    bb.u4 = bv1; acc[1] = __builtin_amdgcn_mfma_f32_16x16x32_f16(fh0.v8, bb.v8, acc[1], 0, 0, 0);
    bb.u4 = bv2; acc[2] = __builtin_amdgcn_mfma_f32_16x16x32_f16(fh0.v8, bb.v8, acc[2], 0, 0, 0);
    bb.u4 = bv3; acc[3] = __builtin_amdgcn_mfma_f32_16x16x32_f16(fh0.v8, bb.v8, acc[3], 0, 0, 0);
    bb.u4 = bv4; acc[0] = __builtin_amdgcn_mfma_f32_16x16x32_f16(fh1.v8, bb.v8, acc[0], 0, 0, 0);
    bb.u4 = bv5; acc[1] = __builtin_amdgcn_mfma_f32_16x16x32_f16(fh1.v8, bb.v8, acc[1], 0, 0, 0);
    bb.u4 = bv6; acc[2] = __builtin_amdgcn_mfma_f32_16x16x32_f16(fh1.v8, bb.v8, acc[2], 0, 0, 0);
    bb.u4 = bv7; acc[3] = __builtin_amdgcn_mfma_f32_16x16x32_f16(fh1.v8, bb.v8, acc[3], 0, 0, 0);
  }

  // ---- epilogue: fused BN + ReLU, per-wave LDS transpose, coalesced store ----
#pragma unroll
  for (int nt = 0; nt < 4; ++nt) {
    int o = nt * 16 + r;
    float sc = bnS[o], sh = bnB[o];
#pragma unroll
    for (int j = 0; j < 4; ++j)
      o_lds[wv][o * 17 + g * 4 + j] = fmaxf(acc[nt][j] * sc + sh, 0.f);
  }
  // no barrier: each wave reads only its own region (lgkmcnt ordering)
  int px = lane & 15, og = lane >> 4;
#pragma unroll
  for (int o4 = 0; o4 < 16; ++o4) {
    int o = o4 * 4 + og;
    out[(size_t)(b * 64 + o) * HW + hwbw + px] = o_lds[wv][o * 17 + px];
  }
}

extern "C" void kernel_launch(void* const* d_in, const int* in_sizes, int n_in,
                              void* d_out, int out_size, void* d_ws, size_t ws_size,
                              hipStream_t stream) {
  const float* x      = (const float*)d_in[0];
  const float* offw   = (const float*)d_in[1];
  const float* offb   = (const float*)d_in[2];
  const float* modw   = (const float*)d_in[3];
  const float* modb   = (const float*)d_in[4];
  const float* weight = (const float*)d_in[5];
  const float* bias   = (const float*)d_in[6];
  const float* gamma  = (const float*)d_in[7];
  const float* beta   = (const float*)d_in[8];
  const float* mean   = (const float*)d_in[9];
  const float* var    = (const float*)d_in[10];

  char* ws = (char*)d_ws;
  uint4*     w4    = (uint4*)(ws + OFF_W4);
  _Float16*  xTh   = (_Float16*)(ws + OFF_XT);
  unsigned*  xybuf = (unsigned*)(ws + OFF_XY);
  _Float16*  wB    = (_Float16*)(ws + OFF_WB);
  _Float16*  wOff  = (_Float16*)(ws + OFF_WO);
  float*     bnS   = (float*)(ws + OFF_BN);
  float*     bnB   = bnS + 64;

  prep_kernel<<<217, 256, 0, stream>>>(weight, offw, modw, bias, gamma, beta,
                                       mean, var, wB, wOff, bnS, bnB);
  transpose_x_kernel<<<1152, 256, 0, stream>>>(x, xTh);
  conv_offsets_kernel<<<2304, 256, 0, stream>>>(xTh, wOff, offb, modb, w4, xybuf);
  dcn_main_kernel<<<1152, 256, 0, stream>>>(xTh, w4, xybuf, wB, bnS, bnB,
                                            (float*)d_out);
}

// Round 8
// 106.791 us; speedup vs baseline: 1.2090x; 1.2090x over previous
//
#include <hip/hip_runtime.h>
#include <hip/hip_bf16.h>
#include <hip/hip_fp16.h>
#include <math.h>

#define BB 8
#define HH 96
#define WW 96
#define HW 9216
#define BN_EPS 1e-5f

typedef _Float16 f16x8 __attribute__((ext_vector_type(8)));
typedef float f32x4 __attribute__((ext_vector_type(4)));

union HU { _Float16 h; unsigned short u; };

// ---- workspace layout (bytes) ----
#define OFF_W4   0
#define SZ_W4    (BB*9*HW*16)          // float4 per (b,k,pixel)
#define OFF_XT   (OFF_W4 + SZ_W4)
#define SZ_XT    (BB*HW*64*2)          // fp16 x transposed (B,H,W,C)
#define OFF_XY   (OFF_XT + SZ_XT)
#define SZ_XY    (BB*9*HW*4)           // packed clamped tap indices
#define OFF_WB   (OFF_XY + SZ_XY)
#define SZ_WB    (64*576*2)            // wB[o][k*64+c] fp16 (main conv)
#define OFF_WO   (OFF_WB + SZ_WB)
#define SZ_WO    (32*576*2)            // wOff[oc][kk*64+c] fp16
#define OFF_BN   (OFF_WO + SZ_WO)
#define SZ_BN    (64*2*4)              // bnS[64], bnB[64]

// ---------------- prep: weight transposes + BN fold ----------------
__global__ __launch_bounds__(256) void prep_kernel(
    const float* __restrict__ weight, const float* __restrict__ offw,
    const float* __restrict__ modw,
    const float* __restrict__ bias, const float* __restrict__ gamma,
    const float* __restrict__ beta, const float* __restrict__ mean,
    const float* __restrict__ var,
    _Float16* __restrict__ wB, _Float16* __restrict__ wOff,
    float* __restrict__ bnS, float* __restrict__ bnB) {
  int tid = blockIdx.x * 256 + threadIdx.x;
  if (tid < 64 * 576) {
    int o = tid / 576, ck = tid % 576;
    int k = ck >> 6, c = ck & 63;                // ck = k*64 + c
    wB[tid] = (_Float16)weight[o * 576 + c * 9 + k];
  }
  int t2 = tid - 64 * 576;
  if (t2 >= 0 && t2 < 32 * 576) {
    int oc = t2 / 576, kcol = t2 % 576;
    int kk = kcol >> 6, c = kcol & 63;           // kcol = kk*64 + c
    float v = 0.f;
    if (oc < 18)      v = offw[(oc * 64 + c) * 9 + kk];
    else if (oc < 27) v = modw[((oc - 18) * 64 + c) * 9 + kk];
    wOff[t2] = (_Float16)v;
  }
  int t3 = tid - (64 * 576 + 32 * 576);
  if (t3 >= 0 && t3 < 64) {
    float inv = gamma[t3] * rsqrtf(var[t3] + BN_EPS);
    bnS[t3] = inv;
    bnB[t3] = (bias[t3] - mean[t3]) * inv + beta[t3];
  }
}

// ---------------- LDS-tiled transpose x -> (B,H,W,C) fp16 (XCD-swizzled) ----
__global__ __launch_bounds__(256) void transpose_x_kernel(
    const float* __restrict__ x, _Float16* __restrict__ xT) {
  __shared__ float tile[64][65];
  int tid = threadIdx.x;
  int b = blockIdx.x & 7;                        // image b stays on one XCD
  int hwb = (blockIdx.x >> 3) * 64;
  int col = tid & 63, g = tid >> 6;
  float r[16];
#pragma unroll
  for (int it = 0; it < 16; ++it)
    r[it] = x[(b * 64 + it * 4 + g) * HW + hwb + col]; // coalesced 256B
  __builtin_amdgcn_sched_barrier(0);
#pragma unroll
  for (int it = 0; it < 16; ++it)
    tile[it * 4 + g][col] = r[it];
  __syncthreads();
#pragma unroll
  for (int it = 0; it < 16; ++it) {
    int p = it * 4 + g;
    xT[(size_t)(b * HW + hwb + p) * 64 + col] = (_Float16)tile[col][p];
  }
}

// ---------------- offset/mod conv via MFMA + fold into sample weights ----------------
__global__ __launch_bounds__(256, 8) void conv_offsets_kernel(
    const _Float16* __restrict__ xTh, const _Float16* __restrict__ wOff,
    const float* __restrict__ offb, const float* __restrict__ modb,
    float4* __restrict__ w4, unsigned* __restrict__ xy) {
  __shared__ __attribute__((aligned(16))) _Float16 sN[3 * 34 * 70]; // stride-70 pad
  __shared__ float o_off[32 * 33];

  int tid = threadIdx.x;
  int lane = tid & 63;
  int wv = __builtin_amdgcn_readfirstlane(tid >> 6);

  int bi = blockIdx.x;                                  // 8b x 288 tiles
  int b = bi & 7, rem = bi >> 3;                        // XCD-swizzled
  int h = rem / 3, w0 = (rem % 3) * 32;

  // ---- stage 3 rows x 34 cols x 64 ch: batch-load to regs, then ds_write ----
  const _Float16* xb = xTh + (size_t)b * HW * 64;
  _Float16 sv[26];
#pragma unroll
  for (int i = 0; i < 26; ++i) {
    int p = wv + 4 * i;
    _Float16 v = (_Float16)0.f;
    if (p < 102) {
      int row = p / 34, col = p - row * 34;
      int y = h + row - 1, xx = w0 + col - 1;
      if ((y >= 0) && (y < HH) && (xx >= 0) && (xx < WW))
        v = xb[(size_t)(y * WW + xx) * 64 + lane];
    }
    sv[i] = v;
  }
  __builtin_amdgcn_sched_barrier(0);
#pragma unroll
  for (int i = 0; i < 26; ++i) {
    int p = wv + 4 * i;
    if (p < 102) {
      int row = p / 34, col = p - row * 34;
      sN[(row * 34 + col) * 70 + lane] = sv[i];
    }
  }
  __syncthreads();

  // ---- MFMA: C[32 px][32 oc], wave = (m-tile, n-tile) quadrant ----
  int r = lane & 15, g = lane >> 4;
  int mt = wv >> 1, nt = wv & 1;
  int px = mt * 16 + r;
  const _Float16* bp = wOff + (nt * 16 + r) * 576 + g * 8;
  f32x4 acc = {0.f, 0.f, 0.f, 0.f};
#pragma unroll
  for (int s = 0; s < 18; ++s) {
    int kk = s >> 1, ky = kk / 3, kx = kk - ky * 3;
    f16x8 a = *(const f16x8*)&sN[(ky * 34 + px + kx) * 70 + (s & 1) * 32 + g * 8];
    f16x8 bb = *(const f16x8*)(bp + s * 32);
    acc = __builtin_amdgcn_mfma_f32_16x16x32_f16(a, bb, acc, 0, 0, 0);
  }
#pragma unroll
  for (int j = 0; j < 4; ++j)
    o_off[(mt * 16 + g * 4 + j) * 33 + nt * 16 + r] = acc[j];
  __syncthreads();

  // ---- fold: sigmoid + bilinear weights + clamped taps, write w4/xy ----
  for (int it = tid; it < 288; it += 256) {
    int pxx = it & 31, k = it >> 5;
    int ky = k / 3, kx = k - ky * 3;
    int w = w0 + pxx;

    float offy = o_off[pxx * 33 + 2 * k]     + offb[2 * k];
    float offx = o_off[pxx * 33 + 2 * k + 1] + offb[2 * k + 1];
    float mod  = 2.f / (1.f + __expf(-(o_off[pxx * 33 + 18 + k] + modb[k])));

    float py  = (float)(h - 1 + ky) + offy;
    float px_ = (float)(w - 1 + kx) + offx;
    float y0f = floorf(py), x0f = floorf(px_);
    float dy = py - y0f, dx = px_ - x0f;
    int y0 = (int)y0f, x0 = (int)x0f;
    int y1 = y0 + 1, x1 = x0 + 1;
    bool vy0 = (y0 >= 0) && (y0 < HH), vy1 = (y1 >= 0) && (y1 < HH);
    bool vx0 = (x0 >= 0) && (x0 < WW), vx1 = (x1 >= 0) && (x1 < WW);
    float w00 = (vy0 && vx0) ? (1.f - dy) * (1.f - dx) * mod : 0.f;
    float w01 = (vy0 && vx1) ? (1.f - dy) * dx * mod : 0.f;
    float w10 = (vy1 && vx0) ? dy * (1.f - dx) * mod : 0.f;
    float w11 = (vy1 && vx1) ? dy * dx * mod : 0.f;
    int y0c = min(max(y0, 0), HH - 1), y1c = min(max(y1, 0), HH - 1);
    int x0c = min(max(x0, 0), WW - 1), x1c = min(max(x1, 0), WW - 1);
    unsigned pk = (unsigned)y0c | ((unsigned)y1c << 8) |
                  ((unsigned)x0c << 16) | ((unsigned)x1c << 24);
    int idx = (b * 9 + k) * HW + h * WW + w;
    w4[idx] = make_float4(w00, w01, w10, w11);
    xy[idx] = pk;
  }
}

__device__ __forceinline__ float hf(unsigned u) {
  HU h; h.u = (unsigned short)u; return (float)h.h;
}

// ---------------- fused deformable sample + MFMA GEMM + BN + ReLU ----------------
// Round-5 structure, but phase-A tap gathers are inline-asm global_load_ushort
// with "=v" outputs: forces 36(+36 pipelined) loads in flight per wave.
// Counted vmcnt(36) waits + sched_barrier fences (rules #18 / T4 pattern).
__global__ __launch_bounds__(256, 4) void dcn_main_kernel(
    const _Float16* __restrict__ xT,
    const float4* __restrict__ w4, const unsigned* __restrict__ xy,
    const _Float16* __restrict__ wB,
    const float* __restrict__ bnS, const float* __restrict__ bnB,
    float* __restrict__ out) {
  __shared__ __attribute__((aligned(16))) _Float16 s_A[16 * 584];
  float* o_lds = (float*)s_A;                          // aliased after barrier

  int tid = threadIdx.x;
  int lane = tid & 63;
  int wv = __builtin_amdgcn_readfirstlane(tid >> 6);

  int bi = blockIdx.x;                                 // 8b x 576 tiles
  int b = bi & 7, t = bi >> 3;                         // XCD-swizzled: image->XCD
  int h = t / 6, w0 = (t - (t / 6) * 6) * 16;
  int hwrow = h * WW + w0;

  const _Float16* xb = xT + (size_t)b * HW * 64;
  unsigned lane2 = (unsigned)(lane << 1);

  float4 wjA[9], wjB[9];
  unsigned rA[36], rB[36];

  // issue: 9 wave-uniform packets (s_loads) + 36 forced-live asm tap loads
#define ISSUE(RES, WJ, P)                                                    \
  {                                                                          \
    int hw = hwrow + wv * 4 + (P);                                           \
    _Pragma("unroll")                                                        \
    for (int k = 0; k < 9; ++k) {                                            \
      int idx = (b * 9 + k) * HW + hw;                                       \
      unsigned q = xy[idx];                                                  \
      WJ[k] = w4[idx];                                                       \
      unsigned y0 = q & 255u, y1 = (q >> 8) & 255u;                          \
      unsigned x0 = (q >> 16) & 255u, x1 = q >> 24;                          \
      unsigned s00 = (y0 * WW + x0) << 7, s01 = (y0 * WW + x1) << 7;         \
      unsigned s10 = (y1 * WW + x0) << 7, s11 = (y1 * WW + x1) << 7;         \
      asm volatile("global_load_ushort %0, %1, %2"                           \
                   : "=v"(RES[4 * k + 0]) : "v"(s00 + lane2), "s"(xb));      \
      asm volatile("global_load_ushort %0, %1, %2"                           \
                   : "=v"(RES[4 * k + 1]) : "v"(s01 + lane2), "s"(xb));      \
      asm volatile("global_load_ushort %0, %1, %2"                           \
                   : "=v"(RES[4 * k + 2]) : "v"(s10 + lane2), "s"(xb));      \
      asm volatile("global_load_ushort %0, %1, %2"                           \
                   : "=v"(RES[4 * k + 3]) : "v"(s11 + lane2), "s"(xb));      \
    }                                                                        \
  }

#define COMBINE(RES, WJ, P)                                                  \
  {                                                                          \
    int pl = wv * 4 + (P);                                                   \
    _Pragma("unroll")                                                        \
    for (int k = 0; k < 9; ++k) {                                            \
      float4 wj = WJ[k];                                                     \
      float s = wj.x * hf(RES[4 * k + 0]) + wj.y * hf(RES[4 * k + 1])        \
              + wj.z * hf(RES[4 * k + 2]) + wj.w * hf(RES[4 * k + 3]);       \
      s_A[pl * 584 + k * 64 + lane] = (_Float16)s;                           \
    }                                                                        \
  }

#define WAITV(N)                                                             \
  asm volatile("s_waitcnt vmcnt(" #N ")" ::: "memory");                      \
  __builtin_amdgcn_sched_barrier(0);

  ISSUE(rA, wjA, 0)
  ISSUE(rB, wjB, 1)
  WAITV(36)
  COMBINE(rA, wjA, 0)
  ISSUE(rA, wjA, 2)
  WAITV(36)
  COMBINE(rB, wjB, 1)
  ISSUE(rB, wjB, 3)
  WAITV(36)
  COMBINE(rA, wjA, 2)
  WAITV(0)
  COMBINE(rB, wjB, 3)

#undef ISSUE
#undef COMBINE
#undef WAITV

  __syncthreads();

  // ---- phase B: [16 x 576] x [576 x 64] fp16 MFMA, wave -> 16 out-channels ----
  int r = lane & 15, g = lane >> 4;
  const _Float16* arow = s_A + r * 584 + g * 8;
  const _Float16* bp = wB + (wv * 16 + r) * 576 + g * 8;
  f32x4 accA = {0.f, 0.f, 0.f, 0.f}, accB = {0.f, 0.f, 0.f, 0.f};
#pragma unroll 3
  for (int s = 0; s < 18; s += 2) {
    f16x8 a0 = *(const f16x8*)(arow + s * 32);
    f16x8 b0 = *(const f16x8*)(bp + s * 32);
    f16x8 a1 = *(const f16x8*)(arow + s * 32 + 32);
    f16x8 b1 = *(const f16x8*)(bp + s * 32 + 32);
    accA = __builtin_amdgcn_mfma_f32_16x16x32_f16(a0, b0, accA, 0, 0, 0);
    accB = __builtin_amdgcn_mfma_f32_16x16x32_f16(a1, b1, accB, 0, 0, 0);
  }

  // ---- epilogue: fused BN + ReLU, LDS transpose, coalesced store ----
  int o = wv * 16 + r;                                 // this lane's out channel
  float sc = bnS[o], sh = bnB[o];
  __syncthreads();                                     // all s_A reads done
#pragma unroll
  for (int j = 0; j < 4; ++j) {
    int px = g * 4 + j;                                // C row = (lane>>4)*4+j
    o_lds[o * 20 + px] = fmaxf((accA[j] + accB[j]) * sc + sh, 0.f);
  }
  __syncthreads();

  int oo = tid >> 2, q = tid & 3;
  float4 u = *(const float4*)&o_lds[oo * 20 + q * 4];
  *(float4*)(out + (size_t)(b * 64 + oo) * HW + hwrow + q * 4) = u;
}

extern "C" void kernel_launch(void* const* d_in, const int* in_sizes, int n_in,
                              void* d_out, int out_size, void* d_ws, size_t ws_size,
                              hipStream_t stream) {
  const float* x      = (const float*)d_in[0];
  const float* offw   = (const float*)d_in[1];
  const float* offb   = (const float*)d_in[2];
  const float* modw   = (const float*)d_in[3];
  const float* modb   = (const float*)d_in[4];
  const float* weight = (const float*)d_in[5];
  const float* bias   = (const float*)d_in[6];
  const float* gamma  = (const float*)d_in[7];
  const float* beta   = (const float*)d_in[8];
  const float* mean   = (const float*)d_in[9];
  const float* var    = (const float*)d_in[10];

  char* ws = (char*)d_ws;
  float4*    w4    = (float4*)(ws + OFF_W4);
  _Float16*  xTh   = (_Float16*)(ws + OFF_XT);
  unsigned*  xybuf = (unsigned*)(ws + OFF_XY);
  _Float16*  wB    = (_Float16*)(ws + OFF_WB);
  _Float16*  wOff  = (_Float16*)(ws + OFF_WO);
  float*     bnS   = (float*)(ws + OFF_BN);
  float*     bnB   = bnS + 64;

  prep_kernel<<<217, 256, 0, stream>>>(weight, offw, modw, bias, gamma, beta,
                                       mean, var, wB, wOff, bnS, bnB);
  transpose_x_kernel<<<1152, 256, 0, stream>>>(x, xTh);
  conv_offsets_kernel<<<2304, 256, 0, stream>>>(xTh, wOff, offb, modb, w4, xybuf);
  dcn_main_kernel<<<4608, 256, 0, stream>>>(xTh, w4, xybuf, wB, bnS, bnB,
                                            (float*)d_out);
}